// Round 8
// baseline (719.621 us; speedup 1.0000x reference)
//
#include <hip/hip_runtime.h>
#include <cfloat>

// Problem constants
#define B_   4
#define C_   512
#define HW_  4096          // 64*64
#define R_   16384         // B_*HW_ rows of x
#define N_   16384         // memory bank rows
#define ALPHA_ 0.1f
#define SCALE_ ((float)(1000.0/49152.0))

typedef unsigned int u32;
typedef unsigned short u16;
typedef unsigned char u8;
typedef __attribute__((ext_vector_type(2))) unsigned long long u64x2;  // 16B = 2 fp8 frags
typedef __attribute__((ext_vector_type(4))) float f32x4;

typedef const __attribute__((address_space(1))) u32* gas_u32;
typedef __attribute__((address_space(3))) u32* las_u32;

__device__ __forceinline__ void async16(const void* g, void* l) {
    __builtin_amdgcn_global_load_lds((gas_u32)g, (las_u32)l, 16, 0, 0);
}

__device__ __forceinline__ u32 pk_fp8x4(float a, float b, float c, float d) {
    u32 v = __builtin_amdgcn_cvt_pk_fp8_f32(a, b, 0, false);   // bytes 0,1
    v = __builtin_amdgcn_cvt_pk_fp8_f32(c, d, v, true);        // bytes 2,3
    return v;
}

__device__ __forceinline__ void ins6(float (&t)[6], float v) {
    if (v < t[5]) {                     // rarely taken
        t[5] = v;
        #pragma unroll
        for (int q = 5; q >= 1; --q) {
            float lo = fminf(t[q-1], t[q]);
            float hi = fmaxf(t[q-1], t[q]);
            t[q-1] = lo; t[q] = hi;
        }
    }
}

// ---------- mem fp32 -> Mb fp8 + m2 (exact fp32 norms) ----------
__global__ void conv_mem_kernel(const float* __restrict__ mem,
                                u8* __restrict__ Mb, float* __restrict__ m2) {
    int w = threadIdx.x >> 6, l = threadIdx.x & 63;
    int row = blockIdx.x * 4 + w;
    const float4* p = (const float4*)(mem + (size_t)row * C_);
    float4 a = p[l], b = p[l + 64];
    float s = a.x*a.x + a.y*a.y + a.z*a.z + a.w*a.w
            + b.x*b.x + b.y*b.y + b.z*b.z + b.w*b.w;
    *(u32*)(Mb + (size_t)row * C_ + l*4)       = pk_fp8x4(a.x, a.y, a.z, a.w);
    *(u32*)(Mb + (size_t)row * C_ + 256 + l*4) = pk_fp8x4(b.x, b.y, b.z, b.w);
    #pragma unroll
    for (int off = 32; off > 0; off >>= 1) s += __shfl_down(s, off);
    if (l == 0) m2[row] = s;
}

// ---------- phi [b][c][n] -> Xb[g][c] fp8 (transpose via LDS) + fused x2 atomics ----------
__global__ void conv_phi_kernel(const float* __restrict__ phi, u8* __restrict__ Xb,
                                float* __restrict__ x2) {
    __shared__ float T[64][65];
    int t = threadIdx.x;
    int n0 = blockIdx.x * 64, c0 = blockIdx.y * 64, b = blockIdx.z;
    const float* src = phi + ((size_t)b * C_ + c0) * HW_ + n0;
    int l = t & 63, cg = t >> 6;
    float sq = 0.f;
    #pragma unroll
    for (int p = 0; p < 16; ++p) {
        int c = cg + p * 4;
        float v = src[(size_t)c * HW_ + l];      // coalesced along n
        T[c][l] = v;
        sq = fmaf(v, v, sq);
    }
    atomicAdd(&x2[(size_t)b * HW_ + n0 + l], sq);
    __syncthreads();
    int cq = t & 15, gl0 = t >> 4;
    #pragma unroll
    for (int p = 0; p < 4; ++p) {
        int gl = gl0 + p * 16;
        u32 v = pk_fp8x4(T[cq*4+0][gl], T[cq*4+1][gl],
                         T[cq*4+2][gl], T[cq*4+3][gl]);
        size_t g = (size_t)b * HW_ + n0 + gl;
        *(u32*)(Xb + g * C_ + c0 + cq*4) = v;
    }
}

// ---------- main GEMM+topk, R17 structure: B SPLIT LDS/GLOBAL.
//  R15/R16 pipe budget (per CU, per 1328-cyc block-stage): ds_read 768 cyc
//  (58%, BINDING), MFMA 620 (47%), sum 105% -> pipes overlap; wall = binding
//  pipe + dep stall. Occupancy levers null (R16). This round halves the
//  binding pipe:
//   * col-groups n=0..3: LDS path unchanged (stage 8KB/stage, swizzle + pc
//     unswizzle byte-identical to R7/R15);
//   * col-groups n=4..7: read DIRECT from global Mb as canonical chunks
//     rq*16 (the A addressing function, HW-verified R12-R15 absmax=0; Mb is
//     canonical so no unswizzle). 8KB/stage region is L1-resident, shared by
//     the 4 waves. Loads issued at stage start, consumed after the LDS half
//     (~250-300 cyc of ds_read+MFMA covers L2 latency; T14 pattern).
//  LDS ds_read demand/stage: 768 -> 384 cyc; staging halves; MFMA (47%)
//  becomes max pipe. L2 adds ~14 TB/s (40% of ceiling).
//  16-row waves, A register-resident, acc 32 AGPR, top 24 (R15, verified).
// ----------
template<int NC>
__global__ __launch_bounds__(256, 3) void gemm_topk_kernel(
    const u8* __restrict__ Xb, const u8* __restrict__ Mb,
    const float* __restrict__ m2, float* __restrict__ P /* [R][NC][6] */) {
    // staging: buf b at b*8192 (64 rows x 128B; half h at +h*4096, row r at r*64)
    // merge phase reuses [0, 24832) after the loop.
    __shared__ __align__(16) u8 smem[32768];
    const int t = threadIdx.x;
    const int w = t >> 6, l = t & 63;
    const int g0  = blockIdx.x * 64;            // block's 64 output rows
    const int n0c = blockIdx.y * (N_ / NC);
    const int mband = w * 16;                   // staging band: 16 M-rows (64 total)
    const int fm  = l & 15;
    const int rq  = l >> 4;
    // frag read: physical chunk = rq ^ ((fm>>1)&3)  (verified conflict-free, R5/R7)
    const int pc  = (rq ^ ((fm >> 1) & 3)) * 16;
    // staging swizzle (verified R7)
    const int srow4 = l >> 2;
    const int soff  = (((l & 3) ^ ((l >> 3) & 3)) * 16);

    // ---- A register-resident for the whole block: wave w owns rows g0+w*16..+16.
    u64x2 ax[4][2];
    {
        const u8* Xr = Xb + (size_t)(g0 + w*16 + fm) * C_ + rq * 16;
        #pragma unroll
        for (int s = 0; s < 4; ++s) {
            ax[s][0] = *(const u64x2*)(Xr + s*128);
            ax[s][1] = *(const u64x2*)(Xr + s*128 + 64);
        }
    }

    float top[4][6];                     // row-slot = g0 + w*16 + rq*4 + j
    #pragma unroll
    for (int s4 = 0; s4 < 4; ++s4)
        #pragma unroll
        for (int q = 0; q < 6; ++q) top[s4][q] = FLT_MAX;

    // prologue: stage (nt=0, s=0) rows n0c..n0c+63, K 0..127 into buf0
    {
        const u8* Msrc = Mb + (size_t)(n0c + mband + srow4) * C_;
        u8* dst = smem + mband * 64;            // wave-uniform; lane lands at +l*16
        async16(Msrc + soff,      dst);         // half 0
        async16(Msrc + 64 + soff, dst + 4096);  // half 1
    }
    __syncthreads();                     // drains vmcnt(0): buf0 ready

    const int NT = N_ / NC / 128;        // 32 at NC=4
    #pragma unroll 1
    for (int nt = 0; nt < NT; ++nt) {
        const int n0 = n0c + nt * 128;

        f32x4 acc[8];
        #pragma unroll
        for (int n = 0; n < 8; ++n) acc[n] = (f32x4)0.f;

        #pragma unroll
        for (int s = 0; s < 4; ++s) {    // K=128 per stage; buf index = s&1 (nt*4 even)
            const int k0 = s * 128;
            // ---- (1) global B for THIS stage: col-groups 4..7, canonical chunk.
            //      Issued first so its vmcnt wait excludes the staging below.
            u64x2 bg0h0, bg0h1, bg1h0, bg1h1, bg2h0, bg2h1, bg3h0, bg3h1;
            {
                const u8* Mr0 = Mb + (size_t)(n0 + 4*16 + fm) * C_ + k0 + rq*16;
                const u8* Mr1 = Mb + (size_t)(n0 + 5*16 + fm) * C_ + k0 + rq*16;
                const u8* Mr2 = Mb + (size_t)(n0 + 6*16 + fm) * C_ + k0 + rq*16;
                const u8* Mr3 = Mb + (size_t)(n0 + 7*16 + fm) * C_ + k0 + rq*16;
                bg0h0 = *(const u64x2*)(Mr0);  bg0h1 = *(const u64x2*)(Mr0 + 64);
                bg1h0 = *(const u64x2*)(Mr1);  bg1h1 = *(const u64x2*)(Mr1 + 64);
                bg2h0 = *(const u64x2*)(Mr2);  bg2h1 = *(const u64x2*)(Mr2 + 64);
                bg3h0 = *(const u64x2*)(Mr3);  bg3h1 = *(const u64x2*)(Mr3 + 64);
            }
            // ---- (2) stage next-stage rows into buf^1 (lands during compute) ----
            {
                const int nt2 = (s == 3) ? nt + 1 : nt;
                const int s2  = (s + 1) & 3;         // compile-time per unrolled s
                if (nt2 < NT) {
                    const u8* Msrc = Mb + (size_t)(n0c + nt2*128 + mband + srow4) * C_
                                        + s2*128;
                    u8* dst = smem + ((s+1)&1)*8192 + mband*64;
                    async16(Msrc + soff,      dst);
                    async16(Msrc + 64 + soff, dst + 4096);
                }
            }
            // ---- (3) LDS half: col-groups 0..3 ----
            const u8* bufp = smem + (s&1)*8192;
            #pragma unroll
            for (int h = 0; h < 2; ++h) {
                const u64x2 a = ax[s][h];            // compile-time [s][h]
                #pragma unroll
                for (int n = 0; n < 4; ++n) {
                    u64x2 bv = *(const u64x2*)(bufp + h*4096 + (n*16 + fm) * 64 + pc);
                    // kf0 = low 8B, kf1 = high 8B: same K-permutation on A and B
                    // -> same dot product (verified R7).
                    acc[n] = __builtin_amdgcn_mfma_f32_16x16x32_fp8_fp8(
                        (long)a.x, (long)bv.x, acc[n], 0, 0, 0);
                    acc[n] = __builtin_amdgcn_mfma_f32_16x16x32_fp8_fp8(
                        (long)a.y, (long)bv.y, acc[n], 0, 0, 0);
                }
            }
            // ---- (4) global half: col-groups 4..7 (canonical chunk = A's) ----
            {
                const u64x2 a0 = ax[s][0], a1 = ax[s][1];
                acc[4] = __builtin_amdgcn_mfma_f32_16x16x32_fp8_fp8((long)a0.x, (long)bg0h0.x, acc[4], 0, 0, 0);
                acc[5] = __builtin_amdgcn_mfma_f32_16x16x32_fp8_fp8((long)a0.x, (long)bg1h0.x, acc[5], 0, 0, 0);
                acc[6] = __builtin_amdgcn_mfma_f32_16x16x32_fp8_fp8((long)a0.x, (long)bg2h0.x, acc[6], 0, 0, 0);
                acc[7] = __builtin_amdgcn_mfma_f32_16x16x32_fp8_fp8((long)a0.x, (long)bg3h0.x, acc[7], 0, 0, 0);
                acc[4] = __builtin_amdgcn_mfma_f32_16x16x32_fp8_fp8((long)a0.y, (long)bg0h0.y, acc[4], 0, 0, 0);
                acc[5] = __builtin_amdgcn_mfma_f32_16x16x32_fp8_fp8((long)a0.y, (long)bg1h0.y, acc[5], 0, 0, 0);
                acc[6] = __builtin_amdgcn_mfma_f32_16x16x32_fp8_fp8((long)a0.y, (long)bg2h0.y, acc[6], 0, 0, 0);
                acc[7] = __builtin_amdgcn_mfma_f32_16x16x32_fp8_fp8((long)a0.y, (long)bg3h0.y, acc[7], 0, 0, 0);
                acc[4] = __builtin_amdgcn_mfma_f32_16x16x32_fp8_fp8((long)a1.x, (long)bg0h1.x, acc[4], 0, 0, 0);
                acc[5] = __builtin_amdgcn_mfma_f32_16x16x32_fp8_fp8((long)a1.x, (long)bg1h1.x, acc[5], 0, 0, 0);
                acc[6] = __builtin_amdgcn_mfma_f32_16x16x32_fp8_fp8((long)a1.x, (long)bg2h1.x, acc[6], 0, 0, 0);
                acc[7] = __builtin_amdgcn_mfma_f32_16x16x32_fp8_fp8((long)a1.x, (long)bg3h1.x, acc[7], 0, 0, 0);
                acc[4] = __builtin_amdgcn_mfma_f32_16x16x32_fp8_fp8((long)a1.y, (long)bg0h1.y, acc[4], 0, 0, 0);
                acc[5] = __builtin_amdgcn_mfma_f32_16x16x32_fp8_fp8((long)a1.y, (long)bg1h1.y, acc[5], 0, 0, 0);
                acc[6] = __builtin_amdgcn_mfma_f32_16x16x32_fp8_fp8((long)a1.y, (long)bg2h1.y, acc[6], 0, 0, 0);
                acc[7] = __builtin_amdgcn_mfma_f32_16x16x32_fp8_fp8((long)a1.y, (long)bg3h1.y, acc[7], 0, 0, 0);
            }

            if (s == 3) {
                // register epilogue: score = m2[c] - 2*dot (x2 added in finalize)
                float m2w[8];
                #pragma unroll
                for (int n = 0; n < 8; ++n) m2w[n] = m2[n0 + n * 16 + fm];
                #pragma unroll
                for (int j = 0; j < 4; ++j) {
                    float d0 = m2w[0] - 2.f * acc[0][j];
                    float d1 = m2w[1] - 2.f * acc[1][j];
                    float d2 = m2w[2] - 2.f * acc[2][j];
                    float d3 = m2w[3] - 2.f * acc[3][j];
                    float d4 = m2w[4] - 2.f * acc[4][j];
                    float d5 = m2w[5] - 2.f * acc[5][j];
                    float d6 = m2w[6] - 2.f * acc[6][j];
                    float d7 = m2w[7] - 2.f * acc[7][j];
                    float vmin = fminf(fminf(fminf(d0, d1), fminf(d2, d3)),
                                       fminf(fminf(d4, d5), fminf(d6, d7)));
                    float (&tt)[6] = top[j];
                    if (vmin < tt[5]) {      // slow path: rare after first tiles
                        ins6(tt, d0); ins6(tt, d1); ins6(tt, d2); ins6(tt, d3);
                        ins6(tt, d4); ins6(tt, d5); ins6(tt, d6); ins6(tt, d7);
                    }
                }
            }
            __syncthreads();   // drains vmcnt(0): next buf staged; buf s&1 free
        }
    }

    // final merge (single pass): per row, combine 16 fm-lanes' top-6 ->
    // per-chunk top-6 partial. 64 rows x stride 97 -> conflict-free reads.
    float* Mg = (float*)smem;            // 64*97 = 6208 floats = 24832 B <= 32768
    #pragma unroll
    for (int j = 0; j < 4; ++j) {
        int lrow = w * 16 + rq * 4 + j;
        #pragma unroll
        for (int q = 0; q < 6; ++q)
            Mg[lrow * 97 + fm * 6 + q] = top[j][q];
    }
    __syncthreads();
    if (t < 64) {
        float t6[6];
        #pragma unroll
        for (int q = 0; q < 6; ++q) t6[q] = FLT_MAX;
        const float* row = Mg + t * 97;
        for (int v = 0; v < 96; ++v) ins6(t6, row[v]);
        float* dst = P + ((size_t)(g0 + t) * NC + blockIdx.y) * 6;
        #pragma unroll
        for (int q = 0; q < 6; ++q) dst[q] = t6[q];
    }
}

// ---------- merge chunks + hinge loss ----------
template<int NC>
__global__ void finalize_kernel(const float* __restrict__ P, const float* __restrict__ x2,
                                const float* __restrict__ rp, float* __restrict__ out) {
    int g = blockIdx.x * 256 + threadIdx.x;
    float t6[6];
    #pragma unroll
    for (int q = 0; q < 6; ++q) t6[q] = FLT_MAX;
    const f32x4* pp = (const f32x4*)(P + (size_t)g * (NC * 6));
    #pragma unroll
    for (int q = 0; q < NC * 6 / 4; ++q) {
        f32x4 v = pp[q];
        ins6(t6, v.x); ins6(t6, v.y); ins6(t6, v.z); ins6(t6, v.w);
    }
    float x2g = x2[g];
    float rv = rp[0], r2 = rv * rv;
    float s = 0.f;
    #pragma unroll
    for (int i = 0; i < 3; ++i) {
        float d = fmaxf(t6[i] + x2g, 0.f);
        s += fmaxf(d - r2, 0.f);
    }
    #pragma unroll
    for (int i = 3; i < 6; ++i) {
        float d = fmaxf(t6[i] + x2g, 0.f);
        s += fmaxf(r2 - d - ALPHA_, 0.f);
    }
    #pragma unroll
    for (int off = 32; off > 0; off >>= 1) s += __shfl_down(s, off);
    __shared__ float red[4];
    int w = threadIdx.x >> 6, l = threadIdx.x & 63;
    if (l == 0) red[w] = s;
    __syncthreads();
    if (threadIdx.x == 0)
        atomicAdd(out, (red[0] + red[1] + red[2] + red[3]) * SCALE_);
}

// ================= Round-1 fp32 fallback (used only if ws too small) =================
#define TM 64
#define TN 64
#define KC 64
#define LDP 68

__global__ void m2_kernel(const float* __restrict__ mem, float* __restrict__ m2) {
    int wave = threadIdx.x >> 6, lane = threadIdx.x & 63;
    int row = blockIdx.x * 4 + wave;
    const float4* p = reinterpret_cast<const float4*>(mem + (size_t)row * C_);
    float4 a = p[lane], b = p[lane + 64];
    float s = a.x*a.x + a.y*a.y + a.z*a.z + a.w*a.w
            + b.x*b.x + b.y*b.y + b.z*b.z + b.w*b.w;
    #pragma unroll
    for (int off = 32; off > 0; off >>= 1) s += __shfl_down(s, off);
    if (lane == 0) m2[row] = s;
}

__global__ void x2f_kernel(const float* __restrict__ phi, float* __restrict__ x2) {
    int g = blockIdx.x * blockDim.x + threadIdx.x;
    int b = g >> 12;
    int n = g & 4095;
    const float* p = phi + (size_t)b * C_ * HW_ + n;
    float s = 0.f;
    #pragma unroll 8
    for (int c = 0; c < C_; ++c) {
        float v = p[(size_t)c * HW_];
        s = fmaf(v, v, s);
    }
    x2[g] = s;
}

__global__ __launch_bounds__(256) void dist_loss_kernel(
    const float* __restrict__ phi, const float* __restrict__ mem,
    const float* __restrict__ rp,  const float* __restrict__ m2,
    const float* __restrict__ x2,  float* __restrict__ out) {
    __shared__ float smem[2 * TM * LDP];
    float* xs = smem;
    float* ms = smem + TM * LDP;
    const int tid = threadIdx.x;
    const int tx = tid & 15, ty = tid >> 4;
    const int g0 = blockIdx.x * TM;
    const int b = g0 >> 12, n0img = g0 & 4095;
    const float* phiB = phi + (size_t)b * C_ * HW_ + n0img;
    float top[4][6];
    #pragma unroll
    for (int i = 0; i < 4; ++i)
        #pragma unroll
        for (int q = 0; q < 6; ++q) top[i][q] = FLT_MAX;
    float x2v[4];
    #pragma unroll
    for (int i = 0; i < 4; ++i) x2v[i] = x2[g0 + ty * 4 + i];
    for (int nt = 0; nt < N_ / TN; ++nt) {
        const int n0 = nt * TN;
        float acc[4][4];
        #pragma unroll
        for (int i = 0; i < 4; ++i)
            #pragma unroll
            for (int j = 0; j < 4; ++j) acc[i][j] = 0.f;
        for (int s = 0; s < C_ / KC; ++s) {
            const int k0 = s * KC;
            {
                int rr = tid & 63, cb = tid >> 6;
                #pragma unroll
                for (int p = 0; p < 16; ++p) {
                    int cc = p * 4 + cb;
                    xs[rr * LDP + cc] = phiB[(size_t)(k0 + cc) * HW_ + rr];
                }
            }
            {
                int kq = tid & 15, cb = tid >> 4;
                #pragma unroll
                for (int p = 0; p < 4; ++p) {
                    int c = p * 16 + cb;
                    float4 v = *reinterpret_cast<const float4*>(
                        mem + (size_t)(n0 + c) * C_ + k0 + kq * 4);
                    ms[(kq*4+0)*LDP + c] = v.x; ms[(kq*4+1)*LDP + c] = v.y;
                    ms[(kq*4+2)*LDP + c] = v.z; ms[(kq*4+3)*LDP + c] = v.w;
                }
            }
            __syncthreads();
            #pragma unroll
            for (int kq = 0; kq < KC / 4; ++kq) {
                float4 xa[4], mb[4];
                #pragma unroll
                for (int i = 0; i < 4; ++i)
                    xa[i] = *reinterpret_cast<const float4*>(&xs[(ty*4+i)*LDP + kq*4]);
                #pragma unroll
                for (int kk = 0; kk < 4; ++kk)
                    mb[kk] = *reinterpret_cast<const float4*>(&ms[(kq*4+kk)*LDP + tx*4]);
                #pragma unroll
                for (int i = 0; i < 4; ++i) {
                    const float xk[4] = {xa[i].x, xa[i].y, xa[i].z, xa[i].w};
                    #pragma unroll
                    for (int kk = 0; kk < 4; ++kk) {
                        const float mc[4] = {mb[kk].x, mb[kk].y, mb[kk].z, mb[kk].w};
                        #pragma unroll
                        for (int j = 0; j < 4; ++j)
                            acc[i][j] = fmaf(xk[kk], mc[j], acc[i][j]);
                    }
                }
            }
            __syncthreads();
        }
        #pragma unroll
        for (int j = 0; j < 4; ++j) {
            float m2v = m2[n0 + tx * 4 + j];
            #pragma unroll
            for (int i = 0; i < 4; ++i) {
                float d = fmaxf(x2v[i] + m2v - 2.f * acc[i][j], 0.f);
                ins6(top[i], d);
            }
        }
    }
    __syncthreads();
    float* mg = smem;
    #pragma unroll
    for (int i = 0; i < 4; ++i)
        #pragma unroll
        for (int q = 0; q < 6; ++q)
            mg[(ty*4+i)*97 + tx*6 + q] = top[i][q];
    __syncthreads();
    if (tid < 64) {
        float t6[6];
        #pragma unroll
        for (int q = 0; q < 6; ++q) t6[q] = FLT_MAX;
        const float* row = mg + tid * 97;
        for (int v = 0; v < 96; ++v) ins6(t6, row[v]);
        float rv = rp[0], r2 = rv * rv;
        float s = fmaxf(t6[0]-r2,0.f) + fmaxf(t6[1]-r2,0.f) + fmaxf(t6[2]-r2,0.f)
                + fmaxf(r2-t6[3]-ALPHA_,0.f) + fmaxf(r2-t6[4]-ALPHA_,0.f)
                + fmaxf(r2-t6[5]-ALPHA_,0.f);
        #pragma unroll
        for (int off = 32; off > 0; off >>= 1) s += __shfl_down(s, off);
        if (tid == 0) atomicAdd(out, s * SCALE_);
    }
}

extern "C" void kernel_launch(void* const* d_in, const int* in_sizes, int n_in,
                              void* d_out, int out_size, void* d_ws, size_t ws_size,
                              hipStream_t stream) {
    const float* phi = (const float*)d_in[0];
    const float* mem = (const float*)d_in[1];
    const float* rp  = (const float*)d_in[2];
    float* out = (float*)d_out;

    const size_t offX  = 0;
    const size_t offM  = (size_t)R_ * C_;                // Xb fp8: 8 MB
    const size_t offx2 = offM + (size_t)N_ * C_;         // Mb fp8: 8 MB
    const size_t offm2 = offx2 + (size_t)R_ * 4;
    const size_t offP  = offm2 + (size_t)N_ * 4;
    const size_t need4 = offP + (size_t)R_ * 4 * 6 * 4;  // ~17.8 MB (NC=4)

    hipMemsetAsync(out, 0, sizeof(float), stream);

    if (ws_size >= need4) {
        u8*    Xb = (u8*)((char*)d_ws + offX);
        u8*    Mb = (u8*)((char*)d_ws + offM);
        float* x2 = (float*)((char*)d_ws + offx2);
        float* m2 = (float*)((char*)d_ws + offm2);
        float* P  = (float*)((char*)d_ws + offP);

        hipMemsetAsync(x2, 0, (size_t)R_ * 4, stream);   // x2 accumulated atomically
        conv_mem_kernel<<<N_ / 4, 256, 0, stream>>>(mem, Mb, m2);
        conv_phi_kernel<<<dim3(HW_ / 64, C_ / 64, B_), 256, 0, stream>>>(phi, Xb, x2);
        gemm_topk_kernel<4><<<dim3(R_ / 64, 4), 256, 0, stream>>>(Xb, Mb, m2, P);
        finalize_kernel<4><<<R_ / 256, 256, 0, stream>>>(P, x2, rp, out);
    } else {
        // fp32 fallback (verified round 1)
        float* m2 = (float*)d_ws;
        float* x2 = m2 + N_;
        m2_kernel<<<N_ / 4, 256, 0, stream>>>(mem, m2);
        x2f_kernel<<<R_ / 256, 256, 0, stream>>>(phi, x2);
        dist_loss_kernel<<<R_ / TM, 256, 0, stream>>>(phi, mem, rp, m2, x2, out);
    }
}

// Round 9
// 346.158 us; speedup vs baseline: 2.0789x; 2.0789x over previous
//
#include <hip/hip_runtime.h>
#include <cfloat>

// Problem constants
#define B_   4
#define C_   512
#define HW_  4096          // 64*64
#define R_   16384         // B_*HW_ rows of x
#define N_   16384         // memory bank rows
#define ALPHA_ 0.1f
#define SCALE_ ((float)(1000.0/49152.0))

typedef unsigned int u32;
typedef unsigned short u16;
typedef unsigned char u8;
typedef __attribute__((ext_vector_type(2))) unsigned long long u64x2;  // 16B = 2 fp8 frags
typedef __attribute__((ext_vector_type(4))) float f32x4;

typedef const __attribute__((address_space(1))) u32* gas_u32;
typedef __attribute__((address_space(3))) u32* las_u32;

__device__ __forceinline__ void async16(const void* g, void* l) {
    __builtin_amdgcn_global_load_lds((gas_u32)g, (las_u32)l, 16, 0, 0);
}

__device__ __forceinline__ u32 pk_fp8x4(float a, float b, float c, float d) {
    u32 v = __builtin_amdgcn_cvt_pk_fp8_f32(a, b, 0, false);   // bytes 0,1
    v = __builtin_amdgcn_cvt_pk_fp8_f32(c, d, v, true);        // bytes 2,3
    return v;
}

__device__ __forceinline__ void ins6(float (&t)[6], float v) {
    if (v < t[5]) {                     // rarely taken
        t[5] = v;
        #pragma unroll
        for (int q = 5; q >= 1; --q) {
            float lo = fminf(t[q-1], t[q]);
            float hi = fmaxf(t[q-1], t[q]);
            t[q-1] = lo; t[q] = hi;
        }
    }
}

// ---------- mem fp32 -> Mb fp8 + m2 (exact fp32 norms) ----------
__global__ void conv_mem_kernel(const float* __restrict__ mem,
                                u8* __restrict__ Mb, float* __restrict__ m2) {
    int w = threadIdx.x >> 6, l = threadIdx.x & 63;
    int row = blockIdx.x * 4 + w;
    const float4* p = (const float4*)(mem + (size_t)row * C_);
    float4 a = p[l], b = p[l + 64];
    float s = a.x*a.x + a.y*a.y + a.z*a.z + a.w*a.w
            + b.x*b.x + b.y*b.y + b.z*b.z + b.w*b.w;
    *(u32*)(Mb + (size_t)row * C_ + l*4)       = pk_fp8x4(a.x, a.y, a.z, a.w);
    *(u32*)(Mb + (size_t)row * C_ + 256 + l*4) = pk_fp8x4(b.x, b.y, b.z, b.w);
    #pragma unroll
    for (int off = 32; off > 0; off >>= 1) s += __shfl_down(s, off);
    if (l == 0) m2[row] = s;
}

// ---------- phi [b][c][n] -> Xb[g][c] fp8 (transpose via LDS) + fused x2 atomics ----------
__global__ void conv_phi_kernel(const float* __restrict__ phi, u8* __restrict__ Xb,
                                float* __restrict__ x2) {
    __shared__ float T[64][65];
    int t = threadIdx.x;
    int n0 = blockIdx.x * 64, c0 = blockIdx.y * 64, b = blockIdx.z;
    const float* src = phi + ((size_t)b * C_ + c0) * HW_ + n0;
    int l = t & 63, cg = t >> 6;
    float sq = 0.f;
    #pragma unroll
    for (int p = 0; p < 16; ++p) {
        int c = cg + p * 4;
        float v = src[(size_t)c * HW_ + l];      // coalesced along n
        T[c][l] = v;
        sq = fmaf(v, v, sq);
    }
    atomicAdd(&x2[(size_t)b * HW_ + n0 + l], sq);
    __syncthreads();
    int cq = t & 15, gl0 = t >> 4;
    #pragma unroll
    for (int p = 0; p < 4; ++p) {
        int gl = gl0 + p * 16;
        u32 v = pk_fp8x4(T[cq*4+0][gl], T[cq*4+1][gl],
                         T[cq*4+2][gl], T[cq*4+3][gl]);
        size_t g = (size_t)b * HW_ + n0 + gl;
        *(u32*)(Xb + g * C_ + c0 + cq*4) = v;
    }
}

// ---------- main GEMM+topk, R18 = R15/R16 verified structure (283us: 16-row
//  waves, A register-resident, M dbuf 2x16KB, 1 barrier/stage) + XCD-AWARE
//  BLOCK REMAP (T1, bijective):
//  R15 diagnosis: all 1024 blocks co-resident; default round-robin puts ALL 4
//  N-chunks (8MB of Mb) on EVERY XCD's 4MB L2 -> thrash -> staging served
//  from L3/HBM (~450-900 cyc) -> the per-barrier vmcnt(0) drain exposes a
//  latency slice on each of 128 barriers (the ~40% stall share).
//  Remap (flat grid 256*NC): xcd=id&7 chooses the chunk half:
//    y = (xcd*NC)>>3, xsub = xcd - y*(8/NC), x = (id>>3) + xsub*(256*NC/8)
//  -> each XCD touches ONE 2MB chunk (L2-resident); staging latency ~200cyc,
//  fully covered by the compute phase. Bijective for NC in {4,8} (checked:
//  (x,y) <-> id). Everything else byte-identical to R16.
// ----------
template<int NC>
__global__ __launch_bounds__(256, 3) void gemm_topk_kernel(
    const u8* __restrict__ Xb, const u8* __restrict__ Mb,
    const float* __restrict__ m2, float* __restrict__ P /* [R][NC][6] */) {
    __shared__ __align__(16) u8 smem[32768];   // M dbuf: buf b at b*16384, half h at +h*8192
    const int t = threadIdx.x;
    const int w = t >> 6, l = t & 63;
    // ---- XCD-aware bijective remap (flat grid of 256*NC blocks) ----
    const int id   = blockIdx.x;
    const int xcd  = id & 7;
    const int cy   = (xcd * NC) >> 3;            // chunk owned by this XCD
    const int xsub = xcd - cy * (8 / NC);        // 0..(8/NC)-1
    const int bx   = (id >> 3) + xsub * (256 * NC / 8);
    const int g0  = bx * 64;                     // block's 64 output rows
    const int n0c = cy * (N_ / NC);
    const int mband = w * 32;                   // staging band of M rows (as R10's rh)
    const int fm  = l & 15;
    const int rq  = l >> 4;
    // frag read: physical chunk = rq ^ ((fm>>1)&3)  (verified conflict-free, R5/R7)
    const int pc  = (rq ^ ((fm >> 1) & 3)) * 16;
    // staging swizzle (verified R7)
    const int srow4 = l >> 2;
    const int soff  = (((l & 3) ^ ((l >> 3) & 3)) * 16);

    // ---- A register-resident for the whole block: wave w owns rows g0+w*16..+16.
    // Per lane: row g0+w*16+fm, canonical logical chunk rq*16 of each 64-B half
    // of each K=128 window. 8 x u64x2 = 32 regs, statically indexed (rule #20).
    u64x2 ax[4][2];
    {
        const u8* Xr = Xb + (size_t)(g0 + w*16 + fm) * C_ + rq * 16;
        #pragma unroll
        for (int s = 0; s < 4; ++s) {
            ax[s][0] = *(const u64x2*)(Xr + s*128);
            ax[s][1] = *(const u64x2*)(Xr + s*128 + 64);
        }
    }

    float top[4][6];                     // row-slot = g0 + w*16 + rq*4 + j
    #pragma unroll
    for (int s4 = 0; s4 < 4; ++s4)
        #pragma unroll
        for (int q = 0; q < 6; ++q) top[s4][q] = FLT_MAX;

    // prologue: stage (nt=0, s=0) into buf0
    {
        const u8* Msrc = Mb + (size_t)(n0c + mband) * C_;
        #pragma unroll
        for (int h = 0; h < 2; ++h)
            #pragma unroll
            for (int i = 0; i < 2; ++i)
                async16(Msrc + (size_t)(i*16 + srow4) * C_ + h*64 + soff,
                        smem + mband*64 + h*8192 + i*1024);
    }
    __syncthreads();                     // drains vmcnt(0): buf0 ready

    const int NT = N_ / NC / 128;        // 32 at NC=4
    #pragma unroll 1
    for (int nt = 0; nt < NT; ++nt) {
        const int n0 = n0c + nt * 128;

        f32x4 acc[8];
        #pragma unroll
        for (int n = 0; n < 8; ++n) acc[n] = (f32x4)0.f;

        #pragma unroll
        for (int s = 0; s < 4; ++s) {    // K=128 per stage; buf index = s&1 (nt*4 even)
            // ---- prefetch next stage into buf^1 (lands during compute below) ----
            {
                const int nt2 = (s == 3) ? nt + 1 : nt;
                const int s2  = (s + 1) & 3;         // compile-time per unrolled s
                if (nt2 < NT) {
                    const u8* Msrc = Mb + (size_t)(n0c + nt2*128 + mband) * C_ + s2*128;
                    u8* dst = smem + ((s+1)&1)*16384 + mband*64;
                    #pragma unroll
                    for (int h = 0; h < 2; ++h)
                        #pragma unroll
                        for (int i = 0; i < 2; ++i)
                            async16(Msrc + (size_t)(i*16 + srow4) * C_ + h*64 + soff,
                                    dst + h*8192 + i*1024);
                }
            }
            // ---- compute current stage from buf s&1 ----
            const u8* bufp = smem + (s&1)*16384;
            #pragma unroll
            for (int h = 0; h < 2; ++h) {
                const u8* Mh = bufp + h * 8192;
                const u64x2 a = ax[s][h];            // compile-time [s][h]
                #pragma unroll
                for (int n = 0; n < 8; ++n) {
                    u64x2 bv = *(const u64x2*)(Mh + (n*16 + fm) * 64 + pc);
                    // kf0 = low 8B, kf1 = high 8B: K-permutation applied
                    // identically to A and B -> same dot product (verified R7).
                    acc[n] = __builtin_amdgcn_mfma_f32_16x16x32_fp8_fp8(
                        (long)a.x, (long)bv.x, acc[n], 0, 0, 0);
                    acc[n] = __builtin_amdgcn_mfma_f32_16x16x32_fp8_fp8(
                        (long)a.y, (long)bv.y, acc[n], 0, 0, 0);
                }
            }

            if (s == 3) {
                // register epilogue: score = m2[c] - 2*dot (x2 added in finalize)
                float m2w[8];
                #pragma unroll
                for (int n = 0; n < 8; ++n) m2w[n] = m2[n0 + n * 16 + fm];
                #pragma unroll
                for (int j = 0; j < 4; ++j) {
                    float d0 = m2w[0] - 2.f * acc[0][j];
                    float d1 = m2w[1] - 2.f * acc[1][j];
                    float d2 = m2w[2] - 2.f * acc[2][j];
                    float d3 = m2w[3] - 2.f * acc[3][j];
                    float d4 = m2w[4] - 2.f * acc[4][j];
                    float d5 = m2w[5] - 2.f * acc[5][j];
                    float d6 = m2w[6] - 2.f * acc[6][j];
                    float d7 = m2w[7] - 2.f * acc[7][j];
                    float vmin = fminf(fminf(fminf(d0, d1), fminf(d2, d3)),
                                       fminf(fminf(d4, d5), fminf(d6, d7)));
                    float (&tt)[6] = top[j];
                    if (vmin < tt[5]) {      // slow path: rare after first tiles
                        ins6(tt, d0); ins6(tt, d1); ins6(tt, d2); ins6(tt, d3);
                        ins6(tt, d4); ins6(tt, d5); ins6(tt, d6); ins6(tt, d7);
                    }
                }
            }
            __syncthreads();   // drains vmcnt(0): next buf staged; buf s&1 free
        }
    }

    // final merge (single pass): per row, combine 16 fm-lanes' top-6 ->
    // per-chunk top-6 partial. 64 rows x stride 97 -> conflict-free reads.
    // The loop's final barrier guarantees all LDS reads are done before reuse.
    float* Mg = (float*)smem;            // 64*97 = 6208 floats = 24832 B <= 32768
    #pragma unroll
    for (int j = 0; j < 4; ++j) {
        int lrow = w * 16 + rq * 4 + j;
        #pragma unroll
        for (int q = 0; q < 6; ++q)
            Mg[lrow * 97 + fm * 6 + q] = top[j][q];
    }
    __syncthreads();
    if (t < 64) {
        float t6[6];
        #pragma unroll
        for (int q = 0; q < 6; ++q) t6[q] = FLT_MAX;
        const float* row = Mg + t * 97;
        for (int v = 0; v < 96; ++v) ins6(t6, row[v]);
        float* dst = P + ((size_t)(g0 + t) * NC + cy) * 6;
        #pragma unroll
        for (int q = 0; q < 6; ++q) dst[q] = t6[q];
    }
}

// ---------- merge chunks + hinge loss ----------
template<int NC>
__global__ void finalize_kernel(const float* __restrict__ P, const float* __restrict__ x2,
                                const float* __restrict__ rp, float* __restrict__ out) {
    int g = blockIdx.x * 256 + threadIdx.x;
    float t6[6];
    #pragma unroll
    for (int q = 0; q < 6; ++q) t6[q] = FLT_MAX;
    const f32x4* pp = (const f32x4*)(P + (size_t)g * (NC * 6));
    #pragma unroll
    for (int q = 0; q < NC * 6 / 4; ++q) {
        f32x4 v = pp[q];
        ins6(t6, v.x); ins6(t6, v.y); ins6(t6, v.z); ins6(t6, v.w);
    }
    float x2g = x2[g];
    float rv = rp[0], r2 = rv * rv;
    float s = 0.f;
    #pragma unroll
    for (int i = 0; i < 3; ++i) {
        float d = fmaxf(t6[i] + x2g, 0.f);
        s += fmaxf(d - r2, 0.f);
    }
    #pragma unroll
    for (int i = 3; i < 6; ++i) {
        float d = fmaxf(t6[i] + x2g, 0.f);
        s += fmaxf(r2 - d - ALPHA_, 0.f);
    }
    #pragma unroll
    for (int off = 32; off > 0; off >>= 1) s += __shfl_down(s, off);
    __shared__ float red[4];
    int w = threadIdx.x >> 6, l = threadIdx.x & 63;
    if (l == 0) red[w] = s;
    __syncthreads();
    if (threadIdx.x == 0)
        atomicAdd(out, (red[0] + red[1] + red[2] + red[3]) * SCALE_);
}

// ================= Round-1 fp32 fallback (used only if ws too small) =================
#define TM 64
#define TN 64
#define KC 64
#define LDP 68

__global__ void m2_kernel(const float* __restrict__ mem, float* __restrict__ m2) {
    int wave = threadIdx.x >> 6, lane = threadIdx.x & 63;
    int row = blockIdx.x * 4 + wave;
    const float4* p = reinterpret_cast<const float4*>(mem + (size_t)row * C_);
    float4 a = p[lane], b = p[lane + 64];
    float s = a.x*a.x + a.y*a.y + a.z*a.z + a.w*a.w
            + b.x*b.x + b.y*b.y + b.z*b.z + b.w*b.w;
    #pragma unroll
    for (int off = 32; off > 0; off >>= 1) s += __shfl_down(s, off);
    if (lane == 0) m2[row] = s;
}

__global__ void x2f_kernel(const float* __restrict__ phi, float* __restrict__ x2) {
    int g = blockIdx.x * blockDim.x + threadIdx.x;
    int b = g >> 12;
    int n = g & 4095;
    const float* p = phi + (size_t)b * C_ * HW_ + n;
    float s = 0.f;
    #pragma unroll 8
    for (int c = 0; c < C_; ++c) {
        float v = p[(size_t)c * HW_];
        s = fmaf(v, v, s);
    }
    x2[g] = s;
}

__global__ __launch_bounds__(256) void dist_loss_kernel(
    const float* __restrict__ phi, const float* __restrict__ mem,
    const float* __restrict__ rp,  const float* __restrict__ m2,
    const float* __restrict__ x2,  float* __restrict__ out) {
    __shared__ float smem[2 * TM * LDP];
    float* xs = smem;
    float* ms = smem + TM * LDP;
    const int tid = threadIdx.x;
    const int tx = tid & 15, ty = tid >> 4;
    const int g0 = blockIdx.x * TM;
    const int b = g0 >> 12, n0img = g0 & 4095;
    const float* phiB = phi + (size_t)b * C_ * HW_ + n0img;
    float top[4][6];
    #pragma unroll
    for (int i = 0; i < 4; ++i)
        #pragma unroll
        for (int q = 0; q < 6; ++q) top[i][q] = FLT_MAX;
    float x2v[4];
    #pragma unroll
    for (int i = 0; i < 4; ++i) x2v[i] = x2[g0 + ty * 4 + i];
    for (int nt = 0; nt < N_ / TN; ++nt) {
        const int n0 = nt * TN;
        float acc[4][4];
        #pragma unroll
        for (int i = 0; i < 4; ++i)
            #pragma unroll
            for (int j = 0; j < 4; ++j) acc[i][j] = 0.f;
        for (int s = 0; s < C_ / KC; ++s) {
            const int k0 = s * KC;
            {
                int rr = tid & 63, cb = tid >> 6;
                #pragma unroll
                for (int p = 0; p < 16; ++p) {
                    int cc = p * 4 + cb;
                    xs[rr * LDP + cc] = phiB[(size_t)(k0 + cc) * HW_ + rr];
                }
            }
            {
                int kq = tid & 15, cb = tid >> 4;
                #pragma unroll
                for (int p = 0; p < 4; ++p) {
                    int c = p * 16 + cb;
                    float4 v = *reinterpret_cast<const float4*>(
                        mem + (size_t)(n0 + c) * C_ + k0 + kq * 4);
                    ms[(kq*4+0)*LDP + c] = v.x; ms[(kq*4+1)*LDP + c] = v.y;
                    ms[(kq*4+2)*LDP + c] = v.z; ms[(kq*4+3)*LDP + c] = v.w;
                }
            }
            __syncthreads();
            #pragma unroll
            for (int kq = 0; kq < KC / 4; ++kq) {
                float4 xa[4], mb[4];
                #pragma unroll
                for (int i = 0; i < 4; ++i)
                    xa[i] = *reinterpret_cast<const float4*>(&xs[(ty*4+i)*LDP + kq*4]);
                #pragma unroll
                for (int kk = 0; kk < 4; ++kk)
                    mb[kk] = *reinterpret_cast<const float4*>(&ms[(kq*4+kk)*LDP + tx*4]);
                #pragma unroll
                for (int i = 0; i < 4; ++i) {
                    const float xk[4] = {xa[i].x, xa[i].y, xa[i].z, xa[i].w};
                    #pragma unroll
                    for (int kk = 0; kk < 4; ++kk) {
                        const float mc[4] = {mb[kk].x, mb[kk].y, mb[kk].z, mb[kk].w};
                        #pragma unroll
                        for (int j = 0; j < 4; ++j)
                            acc[i][j] = fmaf(xk[kk], mc[j], acc[i][j]);
                    }
                }
            }
            __syncthreads();
        }
        #pragma unroll
        for (int j = 0; j < 4; ++j) {
            float m2v = m2[n0 + tx * 4 + j];
            #pragma unroll
            for (int i = 0; i < 4; ++i) {
                float d = fmaxf(x2v[i] + m2v - 2.f * acc[i][j], 0.f);
                ins6(top[i], d);
            }
        }
    }
    __syncthreads();
    float* mg = smem;
    #pragma unroll
    for (int i = 0; i < 4; ++i)
        #pragma unroll
        for (int q = 0; q < 6; ++q)
            mg[(ty*4+i)*97 + tx*6 + q] = top[i][q];
    __syncthreads();
    if (tid < 64) {
        float t6[6];
        #pragma unroll
        for (int q = 0; q < 6; ++q) t6[q] = FLT_MAX;
        const float* row = mg + tid * 97;
        for (int v = 0; v < 96; ++v) ins6(t6, row[v]);
        float rv = rp[0], r2 = rv * rv;
        float s = fmaxf(t6[0]-r2,0.f) + fmaxf(t6[1]-r2,0.f) + fmaxf(t6[2]-r2,0.f)
                + fmaxf(r2-t6[3]-ALPHA_,0.f) + fmaxf(r2-t6[4]-ALPHA_,0.f)
                + fmaxf(r2-t6[5]-ALPHA_,0.f);
        #pragma unroll
        for (int off = 32; off > 0; off >>= 1) s += __shfl_down(s, off);
        if (tid == 0) atomicAdd(out, s * SCALE_);
    }
}

extern "C" void kernel_launch(void* const* d_in, const int* in_sizes, int n_in,
                              void* d_out, int out_size, void* d_ws, size_t ws_size,
                              hipStream_t stream) {
    const float* phi = (const float*)d_in[0];
    const float* mem = (const float*)d_in[1];
    const float* rp  = (const float*)d_in[2];
    float* out = (float*)d_out;

    const size_t offX  = 0;
    const size_t offM  = (size_t)R_ * C_;                // Xb fp8: 8 MB
    const size_t offx2 = offM + (size_t)N_ * C_;         // Mb fp8: 8 MB
    const size_t offm2 = offx2 + (size_t)R_ * 4;
    const size_t offP  = offm2 + (size_t)N_ * 4;
    const size_t need4 = offP + (size_t)R_ * 4 * 6 * 4;  // ~17.8 MB (NC=4)

    hipMemsetAsync(out, 0, sizeof(float), stream);

    if (ws_size >= need4) {
        u8*    Xb = (u8*)((char*)d_ws + offX);
        u8*    Mb = (u8*)((char*)d_ws + offM);
        float* x2 = (float*)((char*)d_ws + offx2);
        float* m2 = (float*)((char*)d_ws + offm2);
        float* P  = (float*)((char*)d_ws + offP);

        hipMemsetAsync(x2, 0, (size_t)R_ * 4, stream);   // x2 accumulated atomically
        conv_mem_kernel<<<N_ / 4, 256, 0, stream>>>(mem, Mb, m2);
        conv_phi_kernel<<<dim3(HW_ / 64, C_ / 64, B_), 256, 0, stream>>>(phi, Xb, x2);
        gemm_topk_kernel<4><<<dim3(256 * 4, 1), 256, 0, stream>>>(Xb, Mb, m2, P);
        finalize_kernel<4><<<R_ / 256, 256, 0, stream>>>(P, x2, rp, out);
    } else {
        // fp32 fallback (verified round 1)
        float* m2 = (float*)d_ws;
        float* x2 = m2 + N_;
        m2_kernel<<<N_ / 4, 256, 0, stream>>>(mem, m2);
        x2f_kernel<<<R_ / 256, 256, 0, stream>>>(phi, x2);
        dist_loss_kernel<<<R_ / TM, 256, 0, stream>>>(phi, mem, rp, m2, x2, out);
    }
}